// Round 2
// baseline (303.065 us; speedup 1.0000x reference)
//
#include <hip/hip_runtime.h>
#include <math.h>

#define BB 16
#define HH 256
#define WW 256
#define NPIX (BB*HH*WW)
#define CH 16      // chunks per column
#define RPC 16     // rows per chunk
#define SUMN (BB*CH*WW)

// ws layout:
//   float d1[2*NPIX]                     (8 MB)  flavor0 = EDT(mask), flavor1 = EDT(1-mask), squared 1D col dists
//   short sumL0,sumL1,sumF0,sumF1[SUMN]  (512 KB) per-(b,chunk,col) last/first zero row (-1 = none)
//   unsigned maxphi[16]; int anyflag[16]; float Sb[16]; float accum[8]

__global__ void init_kernel(unsigned* maxphi, int* anyflag, float* Sb, float* accum) {
    int t = threadIdx.x;
    if (t < 16) { maxphi[t] = 0u; anyflag[t] = 0; Sb[t] = 0.0f; }
    if (t < 8)  accum[t] = 0.0f;
}

// Phase A: per-(b,chunk) local scan. 256 blocks x 256 threads (thread = column j).
// Coalesced row reads. Emits last-zero / first-zero row index per column per flavor.
__global__ __launch_bounds__(256) void colscanA_kernel(const float* __restrict__ targ,
                                                       short* __restrict__ sumL0, short* __restrict__ sumL1,
                                                       short* __restrict__ sumF0, short* __restrict__ sumF1,
                                                       int* __restrict__ anyflag) {
    int b = blockIdx.x >> 4;
    int ch = blockIdx.x & 15;
    int j = threadIdx.x;
    int i0 = ch * RPC;
    const float* m = targ + (b * HH + i0) * WW + j;

    int l0 = -1, l1 = -1, f0 = -1, f1 = -1;
    int any = 0;
    #pragma unroll
    for (int r = 0; r < RPC; ++r) {
        float mv = m[r * WW];
        int i = i0 + r;
        bool z0 = (mv == 0.0f);      // zero pixel of mask
        bool z1 = !z0;               // zero pixel of (1-mask)
        any |= z1;
        if (z0) { l0 = i; if (f0 < 0) f0 = i; }
        if (z1) { l1 = i; if (f1 < 0) f1 = i; }
    }
    int s = blockIdx.x * WW + j;     // == ((b*CH)+ch)*WW + j
    sumL0[s] = (short)l0;  sumL1[s] = (short)l1;
    sumF0[s] = (short)f0;  sumF1[s] = (short)f1;
    if (__any(any) && (threadIdx.x & 63) == 0) atomicOr(&anyflag[b], 1);
}

// Phase B: carry-in finalize. 256 blocks x 256 threads. Each thread resolves its
// chunk's 16 rows for both flavors using cross-chunk carries, writes d1sq.
__global__ __launch_bounds__(256) void colscanB_kernel(const float* __restrict__ targ,
                                                       const short* __restrict__ sumL0, const short* __restrict__ sumL1,
                                                       const short* __restrict__ sumF0, const short* __restrict__ sumF1,
                                                       float* __restrict__ d1) {
    int b = blockIdx.x >> 4;
    int ch = blockIdx.x & 15;
    int j = threadIdx.x;
    int i0 = ch * RPC;

    // carries: nearest zero strictly above this chunk (max of lastz), below (min of firstz)
    int cl[2] = {-1, -1};
    int cf[2] = {100000, 100000};
    for (int c = 0; c < ch; ++c) {
        int s = (b * CH + c) * WW + j;
        cl[0] = max(cl[0], (int)sumL0[s]);
        cl[1] = max(cl[1], (int)sumL1[s]);
    }
    for (int c = ch + 1; c < CH; ++c) {
        int s = (b * CH + c) * WW + j;
        int v0 = (int)sumF0[s]; if (v0 >= 0) cf[0] = min(cf[0], v0);
        int v1 = (int)sumF1[s]; if (v1 >= 0) cf[1] = min(cf[1], v1);
    }

    // zero-bit masks for this chunk's rows
    const float* m = targ + (b * HH + i0) * WW + j;
    unsigned zb0 = 0;
    #pragma unroll
    for (int r = 0; r < RPC; ++r) {
        if (m[r * WW] == 0.0f) zb0 |= (1u << r);
    }
    unsigned zb[2];
    zb[0] = zb0;
    zb[1] = (~zb0) & 0xFFFFu;

    #pragma unroll
    for (int f = 0; f < 2; ++f) {
        unsigned z = zb[f];
        int dup[RPC];
        int nz = cf[f];
        #pragma unroll
        for (int r = RPC - 1; r >= 0; --r) {
            int i = i0 + r;
            if ((z >> r) & 1u) nz = i;
            dup[r] = nz - i;
        }
        int lz = cl[f];
        float* o = d1 + f * NPIX + (b * HH + i0) * WW + j;
        #pragma unroll
        for (int r = 0; r < RPC; ++r) {
            int i = i0 + r;
            if ((z >> r) & 1u) lz = i;
            int ddn = (lz < 0) ? 100000 : (i - lz);
            int d = min(min(ddn, dup[r]), 512);
            float fd = (float)d;
            o[r * WW] = fd * fd;
        }
    }
}

// Fused pass 2 + loss reductions. One block per (b,row). Each lane selects the
// single flavor it needs (mask binary => exactly one of in/out dist is nonzero).
__global__ __launch_bounds__(256) void rowmin_fused_kernel(const float* __restrict__ d1,
                                                           const float* __restrict__ pred,
                                                           const float* __restrict__ targ,
                                                           const int* __restrict__ anyflag,
                                                           unsigned* __restrict__ maxphi,
                                                           float* __restrict__ Sb,
                                                           float* __restrict__ accum) {
    int bi = blockIdx.x;            // b*HH + i
    int b = bi >> 8;
    int j = threadIdx.x;
    __shared__ float srow[2 * WW];  // [0..255] flavor0 (inside), [256..511] flavor1 (outside)
    srow[j]      = d1[bi * WW + j];
    srow[WW + j] = d1[NPIX + bi * WW + j];
    float t = targ[bi * WW + j];
    float x = pred[bi * WW + j];
    __syncthreads();

    bool msk = (t != 0.0f);
    const float4* sel4 = (const float4*)(srow + (msk ? 0 : WW));
    float b0 = 1e30f, b1 = 1e30f;
    float dj0 = (float)j;
    #pragma unroll 8
    for (int k4 = 0; k4 < WW / 8; ++k4) {
        float4 va = sel4[2 * k4];
        float4 vb = sel4[2 * k4 + 1];
        float d0 = dj0, d1v = dj0 - 1.f, d2 = dj0 - 2.f, d3 = dj0 - 3.f;
        float d4 = dj0 - 4.f, d5 = dj0 - 5.f, d6 = dj0 - 6.f, d7 = dj0 - 7.f;
        b0 = fminf(b0, fmaf(d0, d0, va.x));
        b1 = fminf(b1, fmaf(d1v, d1v, va.y));
        b0 = fminf(b0, fmaf(d2, d2, va.z));
        b1 = fminf(b1, fmaf(d3, d3, va.w));
        b0 = fminf(b0, fmaf(d4, d4, vb.x));
        b1 = fminf(b1, fmaf(d5, d5, vb.y));
        b0 = fminf(b0, fmaf(d6, d6, vb.z));
        b1 = fminf(b1, fmaf(d7, d7, vb.w));
        dj0 -= 8.f;
    }
    float best = fminf(b0, b1);
    float dist = sqrtf(best);
    float phi = msk ? -dist : dist;
    if (anyflag[b] == 0) phi = 0.0f;

    float p = 1.0f / (1.0f + expf(-x));
    float sp = p;
    float st = t;
    float spt = p * t;
    float sbce = fmaxf(x, 0.0f) - x * t + log1pf(expf(-fabsf(x)));
    float sphip = phi * p;
    float amax = fabsf(phi);

    #pragma unroll
    for (int off = 32; off > 0; off >>= 1) {
        sp    += __shfl_down(sp,    off, 64);
        st    += __shfl_down(st,    off, 64);
        spt   += __shfl_down(spt,   off, 64);
        sbce  += __shfl_down(sbce,  off, 64);
        sphip += __shfl_down(sphip, off, 64);
        amax   = fmaxf(amax, __shfl_down(amax, off, 64));
    }
    __shared__ float red[4][8];
    int lane = j & 63, wv = j >> 6;
    if (lane == 0) {
        red[wv][0] = sp; red[wv][1] = st; red[wv][2] = spt;
        red[wv][3] = sbce; red[wv][4] = sphip; red[wv][5] = amax;
    }
    __syncthreads();
    if (j == 0) {
        float v0 = red[0][0] + red[1][0] + red[2][0] + red[3][0];
        float v1 = red[0][1] + red[1][1] + red[2][1] + red[3][1];
        float v2 = red[0][2] + red[1][2] + red[2][2] + red[3][2];
        float v3 = red[0][3] + red[1][3] + red[2][3] + red[3][3];
        float v4 = red[0][4] + red[1][4] + red[2][4] + red[3][4];
        float v5 = fmaxf(fmaxf(red[0][5], red[1][5]), fmaxf(red[2][5], red[3][5]));
        atomicAdd(&accum[0], v0);
        atomicAdd(&accum[1], v1);
        atomicAdd(&accum[2], v2);
        atomicAdd(&accum[3], v3);
        atomicAdd(&Sb[b], v4);
        atomicMax(&maxphi[b], __float_as_uint(v5));
    }
}

__global__ void final_kernel(const float* __restrict__ accum,
                             const float* __restrict__ Sb,
                             const unsigned* __restrict__ maxphi,
                             float* __restrict__ out) {
    float sp = accum[0], st = accum[1], spt = accum[2], sbce = accum[3];
    float sbnd = 0.0f;
    #pragma unroll
    for (int b = 0; b < BB; ++b) {
        float denom = __uint_as_float(maxphi[b]) + 1e-8f;
        sbnd += Sb[b] / denom;
    }
    float dice = 1.0f - (2.0f * spt + 1e-6f) / (sp + st + 1e-6f);
    float invN = 1.0f / (float)NPIX;
    float boundary = sbnd * invN;
    float bce = sbce * invN;
    float alpha = 0.005f;
    float beta = 0.6f - alpha;          // 0.595
    out[0] = (1.0f - beta) * dice + beta * boundary + 0.4f * bce;
}

extern "C" void kernel_launch(void* const* d_in, const int* in_sizes, int n_in,
                              void* d_out, int out_size, void* d_ws, size_t ws_size,
                              hipStream_t stream) {
    (void)in_sizes; (void)n_in; (void)out_size; (void)ws_size;
    const float* pred = (const float*)d_in[0];
    const float* targ = (const float*)d_in[1];
    float* ws = (float*)d_ws;
    float* d1 = ws;                                    // 2*NPIX floats
    short* sumL0 = (short*)(ws + 2 * NPIX);
    short* sumL1 = sumL0 + SUMN;
    short* sumF0 = sumL1 + SUMN;
    short* sumF1 = sumF0 + SUMN;
    unsigned* maxphi = (unsigned*)(sumF1 + SUMN);      // 16
    int* anyflag = (int*)(maxphi + 16);                // 16
    float* Sb = (float*)(anyflag + 16);                // 16
    float* accum = Sb + 16;                            // 8

    init_kernel<<<1, 64, 0, stream>>>(maxphi, anyflag, Sb, accum);
    colscanA_kernel<<<BB * CH, 256, 0, stream>>>(targ, sumL0, sumL1, sumF0, sumF1, anyflag);
    colscanB_kernel<<<BB * CH, 256, 0, stream>>>(targ, sumL0, sumL1, sumF0, sumF1, d1);
    rowmin_fused_kernel<<<BB * HH, 256, 0, stream>>>(d1, pred, targ, anyflag, maxphi, Sb, accum);
    final_kernel<<<1, 1, 0, stream>>>(accum, Sb, maxphi, (float*)d_out);
}

// Round 3
// 200.634 us; speedup vs baseline: 1.5105x; 1.5105x over previous
//
#include <hip/hip_runtime.h>
#include <math.h>

#define BB 16
#define HH 256
#define WW 256
#define NPIX (BB*HH*WW)
#define CH 16      // chunks per column
#define RPC 16     // rows per chunk
#define SUMN (BB*CH*WW)

// ws layout:
//   float d1[2*NPIX]                     (8 MB)  flavor0 = EDT(mask), flavor1 = EDT(1-mask), squared 1D col dists
//   short sumL0,sumL1,sumF0,sumF1[SUMN]  (1 MB)  per-(b,chunk,col) last/first zero row (-1 = none)
//   unsigned maxphi[16]; int anyflag[16]; float Sb[16]; float acc4[64]

__global__ void init_kernel(unsigned* maxphi, int* anyflag, float* Sb, float* acc4) {
    int t = threadIdx.x;
    if (t < 16) { maxphi[t] = 0u; anyflag[t] = 0; Sb[t] = 0.0f; }
    acc4[t] = 0.0f;   // 64 threads
}

// Phase A: per-(b,chunk) local scan. 256 blocks x 256 threads (thread = column j).
__global__ __launch_bounds__(256) void colscanA_kernel(const float* __restrict__ targ,
                                                       short* __restrict__ sumL0, short* __restrict__ sumL1,
                                                       short* __restrict__ sumF0, short* __restrict__ sumF1,
                                                       int* __restrict__ anyflag) {
    int b = blockIdx.x >> 4;
    int ch = blockIdx.x & 15;
    int j = threadIdx.x;
    int i0 = ch * RPC;
    const float* m = targ + (b * HH + i0) * WW + j;

    int l0 = -1, l1 = -1, f0 = -1, f1 = -1;
    int any = 0;
    #pragma unroll
    for (int r = 0; r < RPC; ++r) {
        float mv = m[r * WW];
        int i = i0 + r;
        bool z0 = (mv == 0.0f);      // zero pixel of mask
        bool z1 = !z0;               // zero pixel of (1-mask) == nonzero of mask
        any |= z1;
        if (z0) { l0 = i; if (f0 < 0) f0 = i; }
        if (z1) { l1 = i; if (f1 < 0) f1 = i; }
    }
    int s = blockIdx.x * WW + j;
    sumL0[s] = (short)l0;  sumL1[s] = (short)l1;
    sumF0[s] = (short)f0;  sumF1[s] = (short)f1;
    if (__any(any) && (threadIdx.x & 63) == 0) atomicOr(&anyflag[b], 1);
}

// Phase B: carry-in finalize, writes squared 1D column distances.
__global__ __launch_bounds__(256) void colscanB_kernel(const float* __restrict__ targ,
                                                       const short* __restrict__ sumL0, const short* __restrict__ sumL1,
                                                       const short* __restrict__ sumF0, const short* __restrict__ sumF1,
                                                       float* __restrict__ d1) {
    int b = blockIdx.x >> 4;
    int ch = blockIdx.x & 15;
    int j = threadIdx.x;
    int i0 = ch * RPC;

    int cl[2] = {-1, -1};
    int cf[2] = {100000, 100000};
    for (int c = 0; c < ch; ++c) {
        int s = (b * CH + c) * WW + j;
        cl[0] = max(cl[0], (int)sumL0[s]);
        cl[1] = max(cl[1], (int)sumL1[s]);
    }
    for (int c = ch + 1; c < CH; ++c) {
        int s = (b * CH + c) * WW + j;
        int v0 = (int)sumF0[s]; if (v0 >= 0) cf[0] = min(cf[0], v0);
        int v1 = (int)sumF1[s]; if (v1 >= 0) cf[1] = min(cf[1], v1);
    }

    const float* m = targ + (b * HH + i0) * WW + j;
    unsigned zb0 = 0;
    #pragma unroll
    for (int r = 0; r < RPC; ++r) {
        if (m[r * WW] == 0.0f) zb0 |= (1u << r);
    }
    unsigned zb[2];
    zb[0] = zb0;
    zb[1] = (~zb0) & 0xFFFFu;

    #pragma unroll
    for (int f = 0; f < 2; ++f) {
        unsigned z = zb[f];
        int dup[RPC];
        int nz = cf[f];
        #pragma unroll
        for (int r = RPC - 1; r >= 0; --r) {
            int i = i0 + r;
            if ((z >> r) & 1u) nz = i;
            dup[r] = nz - i;
        }
        int lz = cl[f];
        float* o = d1 + f * NPIX + (b * HH + i0) * WW + j;
        #pragma unroll
        for (int r = 0; r < RPC; ++r) {
            int i = i0 + r;
            if ((z >> r) & 1u) lz = i;
            int ddn = (lz < 0) ? 100000 : (i - lz);
            int d = min(min(ddn, dup[r]), 512);
            float fd = (float)d;
            o[r * WW] = fd * fd;
        }
    }
}

// Fused pass 2 + loss reductions. One block per (b,row).
// Windowed exact min: min over |j-k|<=16 of d1sq[k]+(j-k)^2 is the global min
// iff its value <= 17^2 = 289 (any k outside contributes >= 289; all values
// exact small ints in fp32). Rare per-wave full-scan fallback stays exact.
__global__ __launch_bounds__(256) void rowmin_fused_kernel(const float* __restrict__ d1,
                                                           const float* __restrict__ pred,
                                                           const float* __restrict__ targ,
                                                           const int* __restrict__ anyflag,
                                                           unsigned* __restrict__ maxphi,
                                                           float* __restrict__ Sb,
                                                           float* __restrict__ acc4) {
    int bi = blockIdx.x;            // b*HH + i
    int b = bi >> 8;
    int j = threadIdx.x;
    __shared__ float g[2][289];     // 16-pad | 256 | 16-pad (+1 float skew)
    float t = targ[bi * WW + j];
    float x = pred[bi * WW + j];
    g[0][16 + j] = d1[bi * WW + j];           // d1sq inside
    g[1][16 + j] = d1[NPIX + bi * WW + j];    // d1sq outside
    if (j < 16) {
        g[0][j] = 1e30f; g[1][j] = 1e30f;
        g[0][272 + j] = 1e30f; g[1][272 + j] = 1e30f;
    }
    __syncthreads();

    bool msk = (t != 0.0f);
    const float* bsel = msk ? g[0] : g[1];   // mask=1 -> dist_inside (flavor0)
    float best = 1e30f;
    #pragma unroll
    for (int c = 0; c <= 32; ++c) {
        float C = (float)((16 - c) * (16 - c));   // == (j-k)^2, k = j-16+c
        best = fminf(best, bsel[j + c] + C);
    }
    if (__any((int)(best > 289.0f))) {
        const float* b16 = bsel + 16;
        for (int k = 0; k < WW; ++k) {
            float df = (float)(j - k);
            best = fminf(best, b16[k] + df * df);
        }
    }
    float dd = sqrtf(best);
    float phi = msk ? -dd : dd;
    if (anyflag[b] == 0) phi = 0.0f;

    float p = 1.0f / (1.0f + expf(-x));
    float sp = p;
    float st = t;
    float spt = p * t;
    float sbce = fmaxf(x, 0.0f) - x * t + log1pf(expf(-fabsf(x)));
    float sphip = phi * p;
    float amax = fabsf(phi);

    #pragma unroll
    for (int off = 32; off > 0; off >>= 1) {
        sp    += __shfl_down(sp,    off, 64);
        st    += __shfl_down(st,    off, 64);
        spt   += __shfl_down(spt,   off, 64);
        sbce  += __shfl_down(sbce,  off, 64);
        sphip += __shfl_down(sphip, off, 64);
        amax   = fmaxf(amax, __shfl_down(amax, off, 64));
    }
    __shared__ float red[4][8];
    int lane = j & 63, wv = j >> 6;
    if (lane == 0) {
        red[wv][0] = sp; red[wv][1] = st; red[wv][2] = spt;
        red[wv][3] = sbce; red[wv][4] = sphip; red[wv][5] = amax;
    }
    __syncthreads();
    if (j == 0) {
        float v0 = red[0][0] + red[1][0] + red[2][0] + red[3][0];
        float v1 = red[0][1] + red[1][1] + red[2][1] + red[3][1];
        float v2 = red[0][2] + red[1][2] + red[2][2] + red[3][2];
        float v3 = red[0][3] + red[1][3] + red[2][3] + red[3][3];
        float v4 = red[0][4] + red[1][4] + red[2][4] + red[3][4];
        float v5 = fmaxf(fmaxf(red[0][5], red[1][5]), fmaxf(red[2][5], red[3][5]));
        atomicAdd(&acc4[b * 4 + 0], v0);
        atomicAdd(&acc4[b * 4 + 1], v1);
        atomicAdd(&acc4[b * 4 + 2], v2);
        atomicAdd(&acc4[b * 4 + 3], v3);
        atomicAdd(&Sb[b], v4);
        atomicMax(&maxphi[b], __float_as_uint(v5));
    }
}

__global__ void final_kernel(const float* __restrict__ acc4,
                             const float* __restrict__ Sb,
                             const unsigned* __restrict__ maxphi,
                             float* __restrict__ out) {
    float sp = 0.f, st = 0.f, spt = 0.f, sbce = 0.f, sbnd = 0.f;
    #pragma unroll
    for (int b = 0; b < BB; ++b) {
        sp   += acc4[b * 4 + 0];
        st   += acc4[b * 4 + 1];
        spt  += acc4[b * 4 + 2];
        sbce += acc4[b * 4 + 3];
        float denom = __uint_as_float(maxphi[b]) + 1e-8f;
        sbnd += Sb[b] / denom;
    }
    float dice = 1.0f - (2.0f * spt + 1e-6f) / (sp + st + 1e-6f);
    float invN = 1.0f / (float)NPIX;
    float boundary = sbnd * invN;
    float bce = sbce * invN;
    float alpha = 0.005f;
    float beta = 0.6f - alpha;          // 0.595
    out[0] = (1.0f - beta) * dice + beta * boundary + 0.4f * bce;
}

extern "C" void kernel_launch(void* const* d_in, const int* in_sizes, int n_in,
                              void* d_out, int out_size, void* d_ws, size_t ws_size,
                              hipStream_t stream) {
    (void)in_sizes; (void)n_in; (void)out_size; (void)ws_size;
    const float* pred = (const float*)d_in[0];
    const float* targ = (const float*)d_in[1];
    float* ws = (float*)d_ws;
    float* d1 = ws;                                    // 2*NPIX floats
    short* sumL0 = (short*)(ws + 2 * NPIX);
    short* sumL1 = sumL0 + SUMN;
    short* sumF0 = sumL1 + SUMN;
    short* sumF1 = sumF0 + SUMN;
    unsigned* maxphi = (unsigned*)(sumF1 + SUMN);      // 16
    int* anyflag = (int*)(maxphi + 16);                // 16
    float* Sb = (float*)(anyflag + 16);                // 16
    float* acc4 = Sb + 16;                             // 64

    init_kernel<<<1, 64, 0, stream>>>(maxphi, anyflag, Sb, acc4);
    colscanA_kernel<<<BB * CH, 256, 0, stream>>>(targ, sumL0, sumL1, sumF0, sumF1, anyflag);
    colscanB_kernel<<<BB * CH, 256, 0, stream>>>(targ, sumL0, sumL1, sumF0, sumF1, d1);
    rowmin_fused_kernel<<<BB * HH, 256, 0, stream>>>(d1, pred, targ, anyflag, maxphi, Sb, acc4);
    final_kernel<<<1, 1, 0, stream>>>(acc4, Sb, maxphi, (float*)d_out);
}

// Round 4
// 72.858 us; speedup vs baseline: 4.1597x; 2.7538x over previous
//
#include <hip/hip_runtime.h>
#include <math.h>

#define BB 16
#define HH 256
#define WW 256
#define NPIX (BB*HH*WW)
#define CH 16          // 16-row chunks per column
#define RPC 16
#define ROWS 4         // rows per rowmin block
#define NRB (BB*HH/ROWS)   // 1024 rowmin blocks
#define GSTRIDE 304    // LDS buffer stride (floats)

// ws layout:
//   ushort zb[BB*CH*WW]      (128 KB)  bit r of zb[b,c,j] = (targ[b, c*16+r, j] == 0)
//   float  partials[NRB*8]   (32 KB)   per-block {sp,st,spt,sbce,sphip,amax,anym,pad}

// targ -> zero bitmasks. 256 blocks x 256 threads (thread = column).
__global__ __launch_bounds__(256) void zbuild_kernel(const float* __restrict__ targ,
                                                     unsigned short* __restrict__ zb) {
    int b = blockIdx.x >> 4;
    int ch = blockIdx.x & 15;
    int j = threadIdx.x;
    const float* m = targ + (b * HH + ch * RPC) * WW + j;
    unsigned z = 0;
    #pragma unroll
    for (int r = 0; r < RPC; ++r)
        if (m[r * WW] == 0.0f) z |= (1u << r);
    zb[blockIdx.x * WW + j] = (unsigned short)z;
}

// Fused EDT pass2 + loss partials. One block per 4 rows of one image.
// d1sq (squared 1D column distance) derived in-register from bitmasks;
// LDS used only for the +-16 window exchange across columns.
__global__ __launch_bounds__(256) void rowmin_fused_kernel(const unsigned short* __restrict__ zb,
                                                           const float* __restrict__ pred,
                                                           float* __restrict__ partials) {
    int g = blockIdx.x;
    int b = g >> 6;                 // 64 blocks per image
    int r0 = (g & 63) << 2;         // first row-in-image (multiple of 4, within one chunk)
    int C = r0 >> 4;                // chunk containing all 4 rows
    int rb0 = r0 & 15;
    int j = threadIdx.x;

    // 16 chunk bitmasks for this column (full-column info)
    unsigned zc[CH];
    int anym = 0;
    unsigned zoc = 0;
    #pragma unroll
    for (int c = 0; c < CH; ++c) {
        zc[c] = (unsigned)zb[((b * CH + c) << 8) + j];
        anym |= (((~zc[c]) & 0xFFFFu) != 0u);
        if (c == C) zoc = zc[c];    // compile-time c, runtime predicate: no reg-array spill
    }

    // prefetch pred early (hide latency behind the bit work)
    float x[ROWS];
    #pragma unroll
    for (int r = 0; r < ROWS; ++r)
        x[r] = pred[(((b << 8) + (r0 + r)) << 8) + j];

    __shared__ float gg[ROWS][2][GSTRIDE];   // [0,16) pad | data [16,272) | [272,288) pad
    {
        int buf = threadIdx.x >> 5;          // 8 buffers x 32 pad slots
        int pi = threadIdx.x & 31;
        gg[buf >> 1][buf & 1][(pi < 16) ? pi : (256 + pi)] = 1e30f;
    }

    // derive d1sq for ROWS rows, both flavors (f=0: EDT(mask), f=1: EDT(1-mask))
    #pragma unroll
    for (int f = 0; f < 2; ++f) {
        int la = -1, fb = 100000;
        #pragma unroll
        for (int c = 0; c < CH; ++c) {
            unsigned z = f ? ((~zc[c]) & 0xFFFFu) : zc[c];
            if (c < C && z) la = (c << 4) + (31 - __clz(z));       // last zero above chunk C
        }
        #pragma unroll
        for (int c = CH - 1; c >= 0; --c) {
            unsigned z = f ? ((~zc[c]) & 0xFFFFu) : zc[c];
            if (c > C && z) fb = (c << 4) + (__ffs(z) - 1);        // first zero below chunk C
        }
        unsigned zo = f ? ((~zoc) & 0xFFFFu) : zoc;
        #pragma unroll
        for (int r = 0; r < ROWS; ++r) {
            int rb = rb0 + r;
            int i = r0 + r;
            unsigned below = zo & ((2u << rb) - 1u);               // own-chunk bits <= rb
            int lz = below ? ((C << 4) + (31 - __clz(below))) : la;
            unsigned above = zo & (~((1u << rb) - 1u) & 0xFFFFu);  // own-chunk bits >= rb
            int fz = above ? ((C << 4) + (__ffs(above) - 1)) : fb;
            int da = (lz < 0) ? 100000 : (i - lz);
            int db = fz - i;
            int d = min(min(da, db), 512);                         // BIG = H+W cap, matches ref
            float fd = (float)d;
            gg[r][f][16 + j] = fd * fd;
        }
    }
    __syncthreads();

    float sp = 0.f, st = 0.f, spt = 0.f, sbce = 0.f, sphip = 0.f, amax = 0.f;
    #pragma unroll
    for (int r = 0; r < ROWS; ++r) {
        int rb = rb0 + r;
        bool msk = (((zoc >> rb) & 1u) == 0u);    // mask nonzero at this pixel
        const float* bsel = &gg[r][msk ? 0 : 1][0];
        // exact windowed min: if min over |j-k|<=16 is <= 17^2, it is global
        float best = 1e30f;
        #pragma unroll
        for (int c = 0; c <= 32; ++c) {
            float Cc = (float)((16 - c) * (16 - c));   // == (j-k)^2 for k = j-16+c
            best = fminf(best, bsel[j + c] + Cc);
        }
        if (__any(best > 289.0f)) {                    // rare exact fallback
            const float* bs = bsel + 16;
            for (int k = 0; k < WW; ++k) {
                float df = (float)(j - k);
                best = fminf(best, bs[k] + df * df);
            }
        }
        float dd = sqrtf(best);
        float phi = msk ? -dd : dd;                    // phi = dist_out - dist_in
        float xr = x[r];
        float p = 1.0f / (1.0f + expf(-xr));
        sp += p;
        st += msk ? 1.0f : 0.0f;
        spt += msk ? p : 0.0f;
        sbce += fmaxf(xr, 0.0f) - (msk ? xr : 0.0f) + log1pf(expf(-fabsf(xr)));
        sphip += phi * p;
        amax = fmaxf(amax, fabsf(phi));
    }

    // block reduce 7 values, ONE plain store per block (no atomics)
    float anymf = (float)anym;
    #pragma unroll
    for (int off = 32; off > 0; off >>= 1) {
        sp    += __shfl_down(sp,    off, 64);
        st    += __shfl_down(st,    off, 64);
        spt   += __shfl_down(spt,   off, 64);
        sbce  += __shfl_down(sbce,  off, 64);
        sphip += __shfl_down(sphip, off, 64);
        amax   = fmaxf(amax,  __shfl_down(amax,  off, 64));
        anymf  = fmaxf(anymf, __shfl_down(anymf, off, 64));
    }
    __shared__ float red[4][8];
    int lane = j & 63, wv = j >> 6;
    if (lane == 0) {
        red[wv][0] = sp; red[wv][1] = st; red[wv][2] = spt; red[wv][3] = sbce;
        red[wv][4] = sphip; red[wv][5] = amax; red[wv][6] = anymf;
    }
    __syncthreads();
    if (j == 0) {
        float* o = partials + g * 8;
        #pragma unroll
        for (int q = 0; q < 5; ++q)
            o[q] = red[0][q] + red[1][q] + red[2][q] + red[3][q];
        o[5] = fmaxf(fmaxf(red[0][5], red[1][5]), fmaxf(red[2][5], red[3][5]));
        o[6] = fmaxf(fmaxf(red[0][6], red[1][6]), fmaxf(red[2][6], red[3][6]));
    }
}

// Single-block final reduction: 1024 records -> loss scalar.
__global__ __launch_bounds__(256) void final_kernel(const float* __restrict__ partials,
                                                    float* __restrict__ out) {
    int t = threadIdx.x;
    // thread t's 4 records all belong to image b = t/16 (64 records per image)
    float s0 = 0.f, s1 = 0.f, s2 = 0.f, s3 = 0.f, s4 = 0.f, m5 = 0.f, a6 = 0.f;
    #pragma unroll
    for (int e = 0; e < 4; ++e) {
        const float* rec = partials + ((t * 4 + e) << 3);
        s0 += rec[0]; s1 += rec[1]; s2 += rec[2]; s3 += rec[3];
        s4 += rec[4];
        m5 = fmaxf(m5, rec[5]);
        a6 = fmaxf(a6, rec[6]);
    }
    __shared__ float arr[256][8];
    arr[t][4] = s4; arr[t][5] = m5; arr[t][6] = a6;
    __syncthreads();
    __shared__ float bnd[16];
    if (t < 16) {
        float Sb = 0.f, Mb = 0.f, Ab = 0.f;
        for (int e = 0; e < 16; ++e) {
            Sb += arr[t * 16 + e][4];
            Mb = fmaxf(Mb, arr[t * 16 + e][5]);
            Ab = fmaxf(Ab, arr[t * 16 + e][6]);
        }
        bnd[t] = (Ab != 0.0f) ? (Sb / (Mb + 1e-8f)) : 0.0f;   // zero-mask image drops out
    }
    #pragma unroll
    for (int off = 32; off > 0; off >>= 1) {
        s0 += __shfl_down(s0, off, 64);
        s1 += __shfl_down(s1, off, 64);
        s2 += __shfl_down(s2, off, 64);
        s3 += __shfl_down(s3, off, 64);
    }
    __shared__ float wred[4][4];
    int lane = t & 63, wv = t >> 6;
    if (lane == 0) { wred[wv][0] = s0; wred[wv][1] = s1; wred[wv][2] = s2; wred[wv][3] = s3; }
    __syncthreads();
    if (t == 0) {
        float sp   = wred[0][0] + wred[1][0] + wred[2][0] + wred[3][0];
        float st   = wred[0][1] + wred[1][1] + wred[2][1] + wred[3][1];
        float spt  = wred[0][2] + wred[1][2] + wred[2][2] + wred[3][2];
        float sbce = wred[0][3] + wred[1][3] + wred[2][3] + wred[3][3];
        float sbnd = 0.f;
        #pragma unroll
        for (int bb2 = 0; bb2 < BB; ++bb2) sbnd += bnd[bb2];
        float dice = 1.0f - (2.0f * spt + 1e-6f) / (sp + st + 1e-6f);
        float invN = 1.0f / (float)NPIX;
        float boundary = sbnd * invN;
        float bce = sbce * invN;
        float alpha = 0.005f;
        float beta = 0.6f - alpha;      // 0.595
        out[0] = (1.0f - beta) * dice + beta * boundary + 0.4f * bce;
    }
}

extern "C" void kernel_launch(void* const* d_in, const int* in_sizes, int n_in,
                              void* d_out, int out_size, void* d_ws, size_t ws_size,
                              hipStream_t stream) {
    (void)in_sizes; (void)n_in; (void)out_size; (void)ws_size;
    const float* pred = (const float*)d_in[0];
    const float* targ = (const float*)d_in[1];
    unsigned short* zb = (unsigned short*)d_ws;              // 128 KB
    float* partials = (float*)((char*)d_ws + BB * CH * WW * sizeof(unsigned short));  // 32 KB

    zbuild_kernel<<<BB * CH, 256, 0, stream>>>(targ, zb);
    rowmin_fused_kernel<<<NRB, 256, 0, stream>>>(zb, pred, partials);
    final_kernel<<<1, 256, 0, stream>>>(partials, (float*)d_out);
}

// Round 5
// 71.930 us; speedup vs baseline: 4.2134x; 1.0129x over previous
//
#include <hip/hip_runtime.h>
#include <math.h>

#define BB 16
#define HH 256
#define WW 256
#define NPIX (BB*HH*WW)
#define CH 16          // 16-row chunks per column
#define RPC 16
#define ROWS 8         // rows per rowmin block
#define NRB (BB*HH/ROWS)       // 512 rowmin blocks
#define PADW 4
#define GSTRIDE (WW + 2*PADW)  // 264 floats

// ws layout:
//   ushort zb[BB*CH*WW]   (128 KB)  bit r of zb[b,c,j] = (targ[b, c*16+r, j] == 0)
//   float  partials[NRB*8] (16 KB)  per-block {sp,st,spt,sbce,sphip,amax,anym,pad}

// targ -> zero bitmasks. 256 blocks (one 16-row chunk) x 64 threads (4 cols each).
__global__ __launch_bounds__(64) void zbuild_kernel(const float4* __restrict__ targ4,
                                                    ushort4* __restrict__ zb4) {
    int blk = blockIdx.x;                 // b*16 + ch ; row offset = blk*16
    int t = threadIdx.x;
    const float4* m = targ4 + (size_t)blk * RPC * (WW / 4) + t;
    unsigned z0 = 0, z1 = 0, z2 = 0, z3 = 0;
    #pragma unroll
    for (int r = 0; r < RPC; ++r) {
        float4 v = m[r * (WW / 4)];
        if (v.x == 0.0f) z0 |= 1u << r;
        if (v.y == 0.0f) z1 |= 1u << r;
        if (v.z == 0.0f) z2 |= 1u << r;
        if (v.w == 0.0f) z3 |= 1u << r;
    }
    ushort4 o;
    o.x = (unsigned short)z0; o.y = (unsigned short)z1;
    o.z = (unsigned short)z2; o.w = (unsigned short)z3;
    zb4[blk * (WW / 4) + t] = o;
}

// Fused EDT pass2 + loss partials. One block per 8 rows (within one chunk).
// Column-EDT derived in-register from streamed bitmasks (no register arrays).
// Windowed exact min (|j-k|<=4, bound 25) with rare per-wave full-scan fallback.
__global__ __launch_bounds__(256) void rowmin_fused_kernel(const unsigned short* __restrict__ zb,
                                                           const float* __restrict__ pred,
                                                           float* __restrict__ partials) {
    int g = blockIdx.x;
    int b = g >> 5;                 // 32 blocks per image
    int r0 = (g & 31) << 3;         // first row-in-image (multiple of 8)
    int C = r0 >> 4;                // chunk containing all 8 rows
    int rb0 = r0 & 15;
    int j = threadIdx.x;

    // stream 16 chunk masks: carries + own-chunk mask, no indexed array
    int la0 = -1, la1 = -1;         // last zero strictly above chunk C (flavor 0/1)
    int fb0 = 100000, fb1 = 100000; // first zero strictly below chunk C
    unsigned zoc = 0;
    int anym = 0;
    #pragma unroll
    for (int c = 0; c < CH; ++c) {
        unsigned z = (unsigned)zb[((b * CH + c) << 8) + j];
        unsigned zi = (~z) & 0xFFFFu;
        anym |= (zi != 0u);
        if (c < C) {
            if (z)  la0 = (c << 4) + (31 - __clz(z));
            if (zi) la1 = (c << 4) + (31 - __clz(zi));
        } else if (c > C) {
            if (z  && fb0 == 100000) fb0 = (c << 4) + (__ffs(z) - 1);
            if (zi && fb1 == 100000) fb1 = (c << 4) + (__ffs(zi) - 1);
        } else {
            zoc = z;
        }
    }
    unsigned zoc1 = (~zoc) & 0xFFFFu;

    // prefetch pred
    float x[ROWS];
    #pragma unroll
    for (int r = 0; r < ROWS; ++r)
        x[r] = pred[(((b << 8) + (r0 + r)) << 8) + j];

    __shared__ float gg[ROWS][2][GSTRIDE];   // [0,4) pad | data [4,260) | [260,264) pad
    if (j < 2 * ROWS * 2 * PADW) {           // 128 pad slots
        int r = j >> 4, f = (j >> 3) & 1, p = j & 7;
        gg[r][f][(p < PADW) ? p : (WW + p)] = 1e30f;
    }

    #pragma unroll
    for (int r = 0; r < ROWS; ++r) {
        int rb = rb0 + r;
        int i = r0 + r;
        // flavor 0 (EDT of mask: zeros where mask==0)
        unsigned below = zoc & ((2u << rb) - 1u);
        int lz = below ? ((C << 4) + (31 - __clz(below))) : la0;
        unsigned above = zoc & (0xFFFFu & ~((1u << rb) - 1u));
        int fz = above ? ((C << 4) + (__ffs(above) - 1)) : fb0;
        int da = (lz < 0) ? 100000 : (i - lz);
        int d0 = min(min(da, fz - i), 512);
        float f0 = (float)d0;
        gg[r][0][PADW + j] = f0 * f0;
        // flavor 1 (EDT of 1-mask: zeros where mask==1)
        unsigned below1 = zoc1 & ((2u << rb) - 1u);
        int lz1 = below1 ? ((C << 4) + (31 - __clz(below1))) : la1;
        unsigned above1 = zoc1 & (0xFFFFu & ~((1u << rb) - 1u));
        int fz1 = above1 ? ((C << 4) + (__ffs(above1) - 1)) : fb1;
        int da1 = (lz1 < 0) ? 100000 : (i - lz1);
        int d1v = min(min(da1, fz1 - i), 512);
        float f1 = (float)d1v;
        gg[r][1][PADW + j] = f1 * f1;
    }
    __syncthreads();

    float sp = 0.f, st = 0.f, spt = 0.f, sbce = 0.f, sphip = 0.f, amax = 0.f;
    #pragma unroll
    for (int r = 0; r < ROWS; ++r) {
        int rb = rb0 + r;
        bool msk = (((zoc >> rb) & 1u) == 0u);    // mask nonzero at this pixel
        const float* bsel = &gg[r][msk ? 0 : 1][0];
        float best = 1e30f;
        #pragma unroll
        for (int c = 0; c <= 2 * PADW; ++c) {
            float Cc = (float)((PADW - c) * (PADW - c));   // == (j-k)^2, k = j-4+c
            best = fminf(best, bsel[j + c] + Cc);
        }
        if (__any(best > 25.0f)) {                // exact fallback (astronomically rare)
            const float* bs = bsel + PADW;
            for (int k = 0; k < WW; ++k) {
                float df = (float)(j - k);
                best = fminf(best, bs[k] + df * df);
            }
        }
        float dd = sqrtf(best);
        float phi = msk ? -dd : dd;               // phi = dist_out - dist_in
        float xr = x[r];
        float ax = fabsf(xr);
        float q = __expf(-ax);
        float pa = 1.0f / (1.0f + q);             // sigmoid(|x|)
        float p = (xr >= 0.0f) ? pa : q * pa;     // sigmoid(x)
        sp += p;
        st += msk ? 1.0f : 0.0f;
        spt += msk ? p : 0.0f;
        sbce += fmaxf(xr, 0.0f) - (msk ? xr : 0.0f) - __logf(pa);  // log1p(e^-|x|) = -log(pa)
        sphip += phi * p;
        amax = fmaxf(amax, fabsf(phi));
    }

    float anymf = (float)anym;
    #pragma unroll
    for (int off = 32; off > 0; off >>= 1) {
        sp    += __shfl_down(sp,    off, 64);
        st    += __shfl_down(st,    off, 64);
        spt   += __shfl_down(spt,   off, 64);
        sbce  += __shfl_down(sbce,  off, 64);
        sphip += __shfl_down(sphip, off, 64);
        amax   = fmaxf(amax,  __shfl_down(amax,  off, 64));
        anymf  = fmaxf(anymf, __shfl_down(anymf, off, 64));
    }
    __shared__ float red[4][8];
    int lane = j & 63, wv = j >> 6;
    if (lane == 0) {
        red[wv][0] = sp; red[wv][1] = st; red[wv][2] = spt; red[wv][3] = sbce;
        red[wv][4] = sphip; red[wv][5] = amax; red[wv][6] = anymf;
    }
    __syncthreads();
    if (j == 0) {
        float* o = partials + g * 8;
        #pragma unroll
        for (int q2 = 0; q2 < 5; ++q2)
            o[q2] = red[0][q2] + red[1][q2] + red[2][q2] + red[3][q2];
        o[5] = fmaxf(fmaxf(red[0][5], red[1][5]), fmaxf(red[2][5], red[3][5]));
        o[6] = fmaxf(fmaxf(red[0][6], red[1][6]), fmaxf(red[2][6], red[3][6]));
    }
}

// Single-block final reduction: 512 records -> loss scalar.
__global__ __launch_bounds__(256) void final_kernel(const float* __restrict__ partials,
                                                    float* __restrict__ out) {
    int t = threadIdx.x;
    // 32 records per image; thread t reads records 2t, 2t+1 (both image t>>4)
    float s0 = 0.f, s1 = 0.f, s2 = 0.f, s3 = 0.f, s4 = 0.f, m5 = 0.f, a6 = 0.f;
    #pragma unroll
    for (int e = 0; e < 2; ++e) {
        const float* rec = partials + ((t * 2 + e) << 3);
        s0 += rec[0]; s1 += rec[1]; s2 += rec[2]; s3 += rec[3];
        s4 += rec[4];
        m5 = fmaxf(m5, rec[5]);
        a6 = fmaxf(a6, rec[6]);
    }
    __shared__ float arr[256][3];
    arr[t][0] = s4; arr[t][1] = m5; arr[t][2] = a6;
    __syncthreads();
    __shared__ float bnd[16];
    if (t < 16) {
        float Sb = 0.f, Mb = 0.f, Ab = 0.f;
        for (int e = 0; e < 16; ++e) {
            Sb += arr[t * 16 + e][0];
            Mb = fmaxf(Mb, arr[t * 16 + e][1]);
            Ab = fmaxf(Ab, arr[t * 16 + e][2]);
        }
        bnd[t] = (Ab != 0.0f) ? (Sb / (Mb + 1e-8f)) : 0.0f;
    }
    #pragma unroll
    for (int off = 32; off > 0; off >>= 1) {
        s0 += __shfl_down(s0, off, 64);
        s1 += __shfl_down(s1, off, 64);
        s2 += __shfl_down(s2, off, 64);
        s3 += __shfl_down(s3, off, 64);
    }
    __shared__ float wred[4][4];
    int lane = t & 63, wv = t >> 6;
    if (lane == 0) { wred[wv][0] = s0; wred[wv][1] = s1; wred[wv][2] = s2; wred[wv][3] = s3; }
    __syncthreads();
    if (t == 0) {
        float sp   = wred[0][0] + wred[1][0] + wred[2][0] + wred[3][0];
        float st   = wred[0][1] + wred[1][1] + wred[2][1] + wred[3][1];
        float spt  = wred[0][2] + wred[1][2] + wred[2][2] + wred[3][2];
        float sbce = wred[0][3] + wred[1][3] + wred[2][3] + wred[3][3];
        float sbnd = 0.f;
        #pragma unroll
        for (int bb2 = 0; bb2 < BB; ++bb2) sbnd += bnd[bb2];
        float dice = 1.0f - (2.0f * spt + 1e-6f) / (sp + st + 1e-6f);
        float invN = 1.0f / (float)NPIX;
        float boundary = sbnd * invN;
        float bce = sbce * invN;
        float alpha = 0.005f;
        float beta = 0.6f - alpha;      // 0.595
        out[0] = (1.0f - beta) * dice + beta * boundary + 0.4f * bce;
    }
}

extern "C" void kernel_launch(void* const* d_in, const int* in_sizes, int n_in,
                              void* d_out, int out_size, void* d_ws, size_t ws_size,
                              hipStream_t stream) {
    (void)in_sizes; (void)n_in; (void)out_size; (void)ws_size;
    const float* pred = (const float*)d_in[0];
    const float* targ = (const float*)d_in[1];
    unsigned short* zb = (unsigned short*)d_ws;   // 128 KB
    float* partials = (float*)((char*)d_ws + BB * CH * WW * sizeof(unsigned short));

    zbuild_kernel<<<BB * CH, 64, 0, stream>>>((const float4*)targ, (ushort4*)zb);
    rowmin_fused_kernel<<<NRB, 256, 0, stream>>>(zb, pred, partials);
    final_kernel<<<1, 256, 0, stream>>>(partials, (float*)d_out);
}